// Round 14
// baseline (15283.295 us; speedup 1.0000x reference)
//
#include <hip/hip_runtime.h>
#include <hip/hip_bf16.h>
#include <stdint.h>
#include <stddef.h>
#include <math.h>

#define HH 512
#define TT 512
#define BB 32
#define XH 3072   // 6*H
#define GH 2560   // 5*H
#define NWG 32    // unit-partition WGs per group
#define UPW 16    // units per WG
#define CL 512    // time-chunk length (1 chunk per layer)
#define NGRP 8    // batch groups
#define RPG 4     // batch rows per group
#define SCOPE __HIP_MEMORY_SCOPE_AGENT

typedef __attribute__((ext_vector_type(8))) short bf16x8;
typedef __attribute__((ext_vector_type(4))) float f32x4;

__device__ __forceinline__ float bf2f(unsigned short u){
  union{float f; unsigned int i;} v; v.i = ((unsigned int)u)<<16; return v.f;
}
__device__ __forceinline__ unsigned short f2bf(float f){
  union{float f; unsigned int i;} v; v.f=f;
  unsigned int x=v.i;
  return (unsigned short)((x + 0x7FFFu + ((x>>16)&1u))>>16);
}
__device__ __forceinline__ float sigm(float x){ return 1.f/(1.f+expf(-x)); }
__device__ __forceinline__ float tanh_f(float x){ return tanhf(x); }

__global__ void fill_sentinel_f(float* out, int n, float v){
  int i = blockIdx.x*blockDim.x + threadIdx.x;
  int stride = gridDim.x*blockDim.x;
  for (; i < n; i += stride) out[i] = v;
}

// ---------------- fp32 -> bf16 conversion (vectorized, grid-stride) ----------
__global__ void conv_f2bf(const float* __restrict__ in, unsigned short* __restrict__ out, int n){
  int i = (blockIdx.x*blockDim.x + threadIdx.x)*4;
  int stride = gridDim.x*blockDim.x*4;
  for (; i < n; i += stride){
    float4 v = *(const float4*)(in + i);
    ushort4 o; o.x=f2bf(v.x); o.y=f2bf(v.y); o.z=f2bf(v.z); o.w=f2bf(v.w);
    *(ushort4*)(out + i) = o;
  }
}

// ------- MFMA bf16 GEMM: C_bf16[M,N] = A_bf16[M,K] @ Bt_bf16[N,K]^T + bias ---
#define BM 128
#define BN 128
#define BKK 32

__global__ __launch_bounds__(256)
void gemm_bt(const unsigned short* __restrict__ A, const unsigned short* __restrict__ Bt,
             const float* __restrict__ bias, unsigned short* __restrict__ C,
             int M, int N, int K)
{
  __shared__ unsigned short Alds[BM*BKK];
  __shared__ unsigned short Blds[BN*BKK];
  const int tid = threadIdx.x;
  const int lane = tid & 63;
  const int w = tid >> 6;
  const int gm = blockIdx.y, gn = blockIdx.x;
  const int wm = (w>>1)*64, wn = (w&1)*64;
  const int l15 = lane & 15, l4 = lane >> 4;
  f32x4 acc[4][4] = {};
  for (int k0 = 0; k0 < K; k0 += BKK){
    __syncthreads();
    #pragma unroll
    for (int it = 0; it < 2; ++it){
      int id2 = it*256 + tid;
      int row = id2 >> 2, kc = (id2 & 3)*8;
      *(bf16x8*)&Alds[row*BKK + kc] = *(const bf16x8*)(A + (size_t)(gm*BM+row)*K + k0 + kc);
      *(bf16x8*)&Blds[row*BKK + kc] = *(const bf16x8*)(Bt + (size_t)(gn*BN+row)*K + k0 + kc);
    }
    __syncthreads();
    bf16x8 af[4], bfv[4];
    #pragma unroll
    for (int i=0;i<4;i++) af[i]  = *(const bf16x8*)&Alds[(wm + i*16 + l15)*BKK + l4*8];
    #pragma unroll
    for (int j=0;j<4;j++) bfv[j] = *(const bf16x8*)&Blds[(wn + j*16 + l15)*BKK + l4*8];
    #pragma unroll
    for (int i=0;i<4;i++)
      #pragma unroll
      for (int j=0;j<4;j++)
        acc[i][j] = __builtin_amdgcn_mfma_f32_16x16x32_bf16(af[i], bfv[j], acc[i][j], 0,0,0);
  }
  #pragma unroll
  for (int i=0;i<4;i++){
    int row0 = gm*BM + wm + i*16 + l4*4;
    #pragma unroll
    for (int j=0;j<4;j++){
      int col = gn*BN + wn + j*16 + l15;
      float bz = bias[col];
      #pragma unroll
      for (int r=0;r<4;r++)
        C[(size_t)(row0+r)*N + col] = f2bf(acc[i][j][r] + bz);
    }
  }
}

// ---- scan v6: 8 groups x 32 WGs x 384 thr; VGPR weights, MFMA dot, ----------
// ---- conflict-free hs layout, slot/go barrier (no atomic-RMW serialization) -
__global__ __launch_bounds__(384)
void lstm_scan_v6(const unsigned short* __restrict__ xp, // [T*B][6H] bf16
                  const float* __restrict__ whh,         // [5H][H] f32
                  const float* __restrict__ masks,       // [T*B] f32
                  unsigned short* __restrict__ abf,      // [T*B][H] bf16 activations
                  float* __restrict__ outF,              // [T*B][H] f32 (L==3) or null
                  float* __restrict__ hT_out, float* __restrict__ cT_out,
                  int* __restrict__ slots,               // [NGRP][NWG][16] zeroed
                  int* __restrict__ go,                  // [NGRP][16] zeroed
                  int reverse)
{
  __shared__ __align__(16) unsigned short hs[16*64*8];   // 16 KB, chunk-linear
  __shared__ float pre[5][RPG][16];
  const int gid = blockIdx.x & 7;
  const int wgi = blockIdx.x >> 3;
  const int tid = threadIdx.x, wv = tid >> 6, lane = tid & 63;
  const int l15 = lane & 15, l4 = lane >> 4;
  int* myslot = slots + (gid*NWG + wgi)*16;
  int* ggo    = go + gid*16;

  for (int i = tid; i < 16*64*8; i += 384) hs[i] = 0;

  // dot waves: B fragments (hi+lo split bf16) in registers, loaded once
  bf16x8 Bhi[16], Blo[16];
  if (wv < 5){
    const float* wrow = whh + ((size_t)(wv*HH + wgi*UPW + l15))*HH + l4*8;
    #pragma unroll
    for (int kc = 0; kc < 16; ++kc){
      float4 v0 = *(const float4*)(wrow + kc*32);
      float4 v1 = *(const float4*)(wrow + kc*32 + 4);
      float vv[8] = {v0.x,v0.y,v0.z,v0.w,v1.x,v1.y,v1.z,v1.w};
      bf16x8 hh, ll;
      #pragma unroll
      for (int j = 0; j < 8; ++j){
        unsigned short hb = f2bf(vv[j]);
        hh[j] = (short)hb;
        ll[j] = (short)f2bf(vv[j] - bf2f(hb));
      }
      Bhi[kc] = hh; Blo[kc] = ll;
    }
  }
  const bool isPw = (wv == 5);
  const int bl = l4 & 3, uu = l15;
  const int b = gid*RPG + bl, u = wgi*UPW + uu;
  float c_st = 0.f, h_st = 0.f;
  // prologue: prefetch xp for first step
  float cxi=0,cxf=0,cxo=0,cxg=0,cxj=0,cxk=0,cmm=0;
  if (isPw){
    const int t0 = reverse ? (TT-1) : 0;
    const size_t xb = ((size_t)t0*BB + b)*XH + u;
    cxi = bf2f(xp[xb]);        cxf = bf2f(xp[xb +   HH]);
    cxo = bf2f(xp[xb + 2*HH]); cxg = bf2f(xp[xb + 3*HH]);
    cxj = bf2f(xp[xb + 4*HH]); cxk = bf2f(xp[xb + 5*HH]);
    cmm = masks[t0*BB + b];
  }
  __syncthreads();   // hs zeroed

  for (int s = 0; s < TT; ++s){
    const int t = reverse ? (TT-1-s) : s;
    // prefetch next step's xp (hides under dot + barrier)
    float nxi=0,nxf=0,nxo=0,nxg=0,nxj=0,nxk=0,nmm=0;
    if (isPw && s+1 < TT){
      const int t1 = reverse ? (t-1) : (t+1);
      const size_t xb = ((size_t)t1*BB + b)*XH + u;
      nxi = bf2f(xp[xb]);        nxf = bf2f(xp[xb +   HH]);
      nxo = bf2f(xp[xb + 2*HH]); nxg = bf2f(xp[xb + 3*HH]);
      nxj = bf2f(xp[xb + 4*HH]); nxk = bf2f(xp[xb + 5*HH]);
      nmm = masks[t1*BB + b];
    }
    if (s > 0){
      const int tp = reverse ? (t+1) : (t-1);
      if (tid < 256){
        // thread i -> chunk (kc, l4, r): conflict-free read layout
        int r = tid & 3, m = tid >> 2, kc = m >> 2, q4 = m & 3;
        *(uint4*)&hs[((kc*64 + q4*16 + r))*8] =
          *(const uint4*)(abf + ((size_t)tp*BB + gid*RPG + r)*HH + kc*32 + q4*8);
      }
      __syncthreads();
      if (wv < 5){
        f32x4 a1 = {0.f,0.f,0.f,0.f}, a2 = {0.f,0.f,0.f,0.f};
        #pragma unroll
        for (int kc = 0; kc < 16; ++kc){
          bf16x8 A = *(const bf16x8*)&hs[(kc*64 + lane)*8];
          a1 = __builtin_amdgcn_mfma_f32_16x16x32_bf16(A, Bhi[kc], a1, 0,0,0);
          a2 = __builtin_amdgcn_mfma_f32_16x16x32_bf16(A, Blo[kc], a2, 0,0,0);
        }
        if (l4 == 0){
          #pragma unroll
          for (int r = 0; r < 4; ++r) pre[wv][r][l15] = a1[r] + a2[r];
        }
      }
    }
    __syncthreads();
    if (isPw){
      float p0=0,p1=0,p2=0,p3=0,p4=0;
      if (s > 0){
        p0 = pre[0][bl][uu]; p1 = pre[1][bl][uu]; p2 = pre[2][bl][uu];
        p3 = pre[3][bl][uu]; p4 = pre[4][bl][uu];
      }
      float ig = sigm(p0 + cxi);
      float fg = sigm(p1 + cxf + 1.0f);
      float og = sigm(p2 + cxo);
      float tg = sigm(p3 + cxg);
      float jg = tanh_f(p4 + cxj);
      float cn = fg*c_st + ig*jg;
      cn = cmm*cn + (1.f-cmm)*c_st;
      float hn = tg*og*tanh_f(cn) + (1.f-tg)*cxk;
      hn = cmm*hn + (1.f-cmm)*h_st;
      c_st = cn; h_st = hn;
      abf[((size_t)t*BB + b)*HH + u] = f2bf(hn);
      if (outF) outF[((size_t)t*BB + b)*HH + u] = hn;
    }
    if (s < TT-1){
      __syncthreads();   // abf stores drained to L2 (vmcnt0 at barrier)
      if (tid == 0){
        const int epoch = s + 1;
        __hip_atomic_store(myslot, epoch, __ATOMIC_RELEASE, SCOPE);
        if (wgi == 0){
          int round = 0;
          for (;;){
            int mn = 0x7fffffff;
            #pragma unroll
            for (int w2 = 1; w2 < NWG; ++w2){
              int v = __hip_atomic_load(slots + (gid*NWG + w2)*16, __ATOMIC_RELAXED, SCOPE);
              mn = v < mn ? v : mn;
            }
            if (mn >= epoch) break;
            if ((++round & 7) == 7)
              (void)__hip_atomic_load(slots + (gid*NWG + 1)*16, __ATOMIC_ACQUIRE, SCOPE);
            __builtin_amdgcn_s_sleep(1);
          }
          (void)__hip_atomic_load(slots + (gid*NWG + 1)*16, __ATOMIC_ACQUIRE, SCOPE);
          __hip_atomic_store(ggo, epoch, __ATOMIC_RELEASE, SCOPE);
        } else {
          int it = 0;
          while (__hip_atomic_load(ggo, __ATOMIC_RELAXED, SCOPE) < epoch){
            if ((++it & 63) == 63)
              (void)__hip_atomic_load(ggo, __ATOMIC_ACQUIRE, SCOPE);
            __builtin_amdgcn_s_sleep(1);
          }
          (void)__hip_atomic_load(ggo, __ATOMIC_ACQUIRE, SCOPE);
        }
      }
      __syncthreads();
    }
    if (isPw){
      cxi=nxi; cxf=nxf; cxo=nxo; cxg=nxg; cxj=nxj; cxk=nxk; cmm=nmm;
    }
  }
  if (isPw){
    hT_out[(size_t)b*HH + u] = h_st;
    cT_out[(size_t)b*HH + u] = c_st;
  }
}

// ------------------------------- launch ---------------------------------------
extern "C" void kernel_launch(void* const* d_in, const int* in_sizes, int n_in,
                              void* d_out, int out_size, void* d_ws, size_t ws_size,
                              hipStream_t stream)
{
  const float* x = nullptr; const float* masks = nullptr;
  const float* wih[4] = {}; const float* bih[4] = {}; const float* whh[4] = {};
  int nw = 0, nb = 0, nh = 0;
  for (int i = 0; i < n_in; ++i){
    const int sz = in_sizes[i];
    const float* p = (const float*)d_in[i];
    if      (sz == TT*BB*HH){ if (!x) x = p; }
    else if (sz == TT*BB)   { if (!masks) masks = p; }
    else if (sz == XH*HH)   { if (nw < 4) wih[nw++] = p; }
    else if (sz == XH)      { if (nb < 4) bih[nb++] = p; }
    else if (sz == GH*HH)   { if (nh < 4) whh[nh++] = p; }
  }
  float* out = (float*)d_out;
  if (!x || !masks || nw != 4 || nb != 4 || nh != 4){
    fill_sentinel_f<<<512, 256, 0, stream>>>(out, out_size, 777.0f);
    return;
  }

  char* ws = (char*)d_ws;
  size_t off = 0;
  auto alloc = [&](size_t bytes)->void*{
    void* p = ws + off; off += (bytes + 255) & ~(size_t)255; return p;
  };
  unsigned short* xbf   = (unsigned short*)alloc((size_t)TT*BB*HH*2);  // 16.8 MB
  unsigned short* abf   = (unsigned short*)alloc((size_t)TT*BB*HH*2);  // 16.8 MB
  unsigned short* wbf   = (unsigned short*)alloc((size_t)XH*HH*2);     //  3.1 MB
  unsigned short* xproj = (unsigned short*)alloc((size_t)TT*BB*XH*2);  // 50.3 MB
  int*            slots = (int*)alloc((size_t)4*NGRP*NWG*16*4);        //  64 KB
  int*            go    = (int*)alloc((size_t)4*NGRP*16*4);            //   2 KB

  (void)hipMemsetAsync(slots, 0, (size_t)4*NGRP*NWG*16*4, stream);
  (void)hipMemsetAsync(go,    0, (size_t)4*NGRP*16*4, stream);

  const int thr = 256;
  auto cgrid = [&](int n){ int g = (n/4 + thr - 1)/thr; return g > 2048 ? 2048 : g; };
  conv_f2bf<<<cgrid(TT*BB*HH), thr, 0, stream>>>(x, xbf, TT*BB*HH);

  float* hn = out + (size_t)TT*BB*HH;
  float* cn = hn + (size_t)4*BB*HH;

  for (int L = 0; L < 4; ++L){
    const int rev = L & 1;
    conv_f2bf<<<cgrid(XH*HH), thr, 0, stream>>>(wih[L], wbf, XH*HH);
    gemm_bt<<<dim3(XH/BN, (TT*BB)/BM), 256, 0, stream>>>(
        (L == 0 ? xbf : abf), wbf, bih[L], xproj, TT*BB, XH, HH);

    lstm_scan_v6<<<NGRP*NWG, 384, 0, stream>>>(
        xproj, whh[L], masks, abf,
        (L == 3) ? out : nullptr,
        hn + (size_t)L*BB*HH, cn + (size_t)L*BB*HH,
        slots + (size_t)L*NGRP*NWG*16, go + (size_t)L*NGRP*16,
        rev);
  }
}

// Round 15
// 10188.589 us; speedup vs baseline: 1.5000x; 1.5000x over previous
//
#include <hip/hip_runtime.h>
#include <hip/hip_bf16.h>
#include <stdint.h>
#include <stddef.h>
#include <math.h>

#define HH 512
#define TT 512
#define BB 32
#define XH 3072   // 6*H
#define GH 2560   // 5*H
#define NWG 32    // unit-partition WGs per group
#define UPW 16    // units per WG
#define NGRP 8    // batch groups
#define RPG 4     // batch rows per group
#define SCOPE __HIP_MEMORY_SCOPE_AGENT
#define WGSC  __HIP_MEMORY_SCOPE_WORKGROUP

typedef __attribute__((ext_vector_type(8))) short bf16x8;
typedef __attribute__((ext_vector_type(4))) float f32x4;
typedef unsigned long long u64;

__device__ __forceinline__ float bf2f(unsigned short u){
  union{float f; unsigned int i;} v; v.i = ((unsigned int)u)<<16; return v.f;
}
__device__ __forceinline__ unsigned short f2bf(float f){
  union{float f; unsigned int i;} v; v.f=f;
  unsigned int x=v.i;
  return (unsigned short)((x + 0x7FFFu + ((x>>16)&1u))>>16);
}
__device__ __forceinline__ float sigm(float x){ return 1.f/(1.f+__expf(-x)); }
__device__ __forceinline__ float tanh_f(float x){ return 1.f - 2.f/(__expf(2.f*x)+1.f); }

__global__ void fill_sentinel_f(float* out, int n, float v){
  int i = blockIdx.x*blockDim.x + threadIdx.x;
  int stride = gridDim.x*blockDim.x;
  for (; i < n; i += stride) out[i] = v;
}

__global__ void conv_f2bf(const float* __restrict__ in, unsigned short* __restrict__ out, int n){
  int i = (blockIdx.x*blockDim.x + threadIdx.x)*4;
  int stride = gridDim.x*blockDim.x*4;
  for (; i < n; i += stride){
    float4 v = *(const float4*)(in + i);
    ushort4 o; o.x=f2bf(v.x); o.y=f2bf(v.y); o.z=f2bf(v.z); o.w=f2bf(v.w);
    *(ushort4*)(out + i) = o;
  }
}

// ------- MFMA bf16 GEMM: C_bf16[M,N] = A_bf16[M,K] @ Bt_bf16[N,K]^T + bias ---
#define BM 128
#define BN 128
#define BKK 32

__global__ __launch_bounds__(256)
void gemm_bt(const unsigned short* __restrict__ A, const unsigned short* __restrict__ Bt,
             const float* __restrict__ bias, unsigned short* __restrict__ C,
             int M, int N, int K)
{
  __shared__ unsigned short Alds[BM*BKK];
  __shared__ unsigned short Blds[BN*BKK];
  const int tid = threadIdx.x;
  const int lane = tid & 63;
  const int w = tid >> 6;
  const int gm = blockIdx.y, gn = blockIdx.x;
  const int wm = (w>>1)*64, wn = (w&1)*64;
  const int l15 = lane & 15, l4 = lane >> 4;
  f32x4 acc[4][4] = {};
  for (int k0 = 0; k0 < K; k0 += BKK){
    __syncthreads();
    #pragma unroll
    for (int it = 0; it < 2; ++it){
      int id2 = it*256 + tid;
      int row = id2 >> 2, kc = (id2 & 3)*8;
      *(bf16x8*)&Alds[row*BKK + kc] = *(const bf16x8*)(A + (size_t)(gm*BM+row)*K + k0 + kc);
      *(bf16x8*)&Blds[row*BKK + kc] = *(const bf16x8*)(Bt + (size_t)(gn*BN+row)*K + k0 + kc);
    }
    __syncthreads();
    bf16x8 af[4], bfv[4];
    #pragma unroll
    for (int i=0;i<4;i++) af[i]  = *(const bf16x8*)&Alds[(wm + i*16 + l15)*BKK + l4*8];
    #pragma unroll
    for (int j=0;j<4;j++) bfv[j] = *(const bf16x8*)&Blds[(wn + j*16 + l15)*BKK + l4*8];
    #pragma unroll
    for (int i=0;i<4;i++)
      #pragma unroll
      for (int j=0;j<4;j++)
        acc[i][j] = __builtin_amdgcn_mfma_f32_16x16x32_bf16(af[i], bfv[j], acc[i][j], 0,0,0);
  }
  #pragma unroll
  for (int i=0;i<4;i++){
    int row0 = gm*BM + wm + i*16 + l4*4;
    #pragma unroll
    for (int j=0;j<4;j++){
      int col = gn*BN + wn + j*16 + l15;
      float bz = bias[col];
      #pragma unroll
      for (int r=0;r<4;r++)
        C[(size_t)(row0+r)*N + col] = f2bf(acc[i][j][r] + bz);
    }
  }
}

// ---- scan v7: role-split waves, relaxed coherence-point atomics, no barriers -
__global__ __launch_bounds__(384)
void lstm_scan_v7(const unsigned short* __restrict__ xp, // [T*B][6H] bf16
                  const float* __restrict__ whh,         // [5H][H] f32
                  const float* __restrict__ masks,       // [T*B] f32
                  unsigned short* __restrict__ abf,      // [T*B][H] bf16 (atomics)
                  float* __restrict__ outF,              // [T*B][H] f32 or null
                  float* __restrict__ hT_out, float* __restrict__ cT_out,
                  int* __restrict__ slots,               // [NGRP][NWG][16] zeroed
                  int* __restrict__ go,                  // [NGRP][16] zeroed
                  int reverse)
{
  __shared__ __align__(16) unsigned short hs[16*64*8];   // 16 KB chunk-linear A
  __shared__ float pre[5][RPG][16];
  __shared__ __align__(8) unsigned short pwl[64];
  __shared__ int A_rdy, pre_cnt;
  const int gid = blockIdx.x & 7;
  const int wgi = blockIdx.x >> 3;
  const int tid = threadIdx.x, wv = tid >> 6, lane = tid & 63;
  const int l15 = lane & 15, l4 = lane >> 4;
  int* myslot   = slots + (gid*NWG + wgi)*16;
  int* slotbase = slots + gid*NWG*16;
  int* ggo      = go + gid*16;

  for (int i = tid; i < 16*64*8; i += 384) hs[i] = 0;
  if (tid == 0){ A_rdy = 0; pre_cnt = 0; }
  __syncthreads();   // the only block-wide barrier

  if (wv < 5){
    // ---------------- dot waves: gate wv, units wgi*16.. ----------------
    bf16x8 Bhi[16], Blo[16];
    {
      const float* wrow = whh + ((size_t)(wv*HH + wgi*UPW + l15))*HH + l4*8;
      #pragma unroll
      for (int kc = 0; kc < 16; ++kc){
        float4 v0 = *(const float4*)(wrow + kc*32);
        float4 v1 = *(const float4*)(wrow + kc*32 + 4);
        float vv[8] = {v0.x,v0.y,v0.z,v0.w,v1.x,v1.y,v1.z,v1.w};
        bf16x8 hh, ll;
        #pragma unroll
        for (int j = 0; j < 8; ++j){
          unsigned short hb = f2bf(vv[j]);
          hh[j] = (short)hb;
          ll[j] = (short)f2bf(vv[j] - bf2f(hb));
        }
        Bhi[kc] = hh; Blo[kc] = ll;
      }
    }
    for (int s = 1; s < TT; ++s){
      const int t  = reverse ? (TT-1-s) : s;
      const int tp = reverse ? (t+1) : (t-1);
      if (wv == 0){
        if (lane == 0){
          while (__hip_atomic_load(ggo, __ATOMIC_RELAXED, SCOPE) < s)
            __builtin_amdgcn_s_sleep(1);
        }
        // stage 4 KB h-tile: 8 relaxed atomic 8B loads/lane -> LDS remap
        const u64* src = (const u64*)(abf + ((size_t)tp*BB + gid*RPG)*HH);
        #pragma unroll
        for (int it = 0; it < 8; ++it){
          int j = it*64 + lane;            // ulong index; 512 total
          u64 v = __hip_atomic_load(&src[j], __ATOMIC_RELAXED, SCOPE);
          int r = j >> 7, ww = j & 127;
          int kc = ww >> 3, ll4 = (ww >> 1) & 3, half = ww & 1;
          *(u64*)&hs[(kc*64 + ll4*16 + r)*8 + half*4] = v;
        }
        __threadfence_block();
        if (lane == 0)
          __hip_atomic_store(&A_rdy, s, __ATOMIC_RELAXED, WGSC);
      } else {
        while (__hip_atomic_load(&A_rdy, __ATOMIC_RELAXED, WGSC) < s){}
      }
      f32x4 a1 = {0.f,0.f,0.f,0.f}, a2 = {0.f,0.f,0.f,0.f};
      #pragma unroll
      for (int kc = 0; kc < 16; ++kc){
        bf16x8 A = *(const bf16x8*)&hs[(kc*64 + lane)*8];
        a1 = __builtin_amdgcn_mfma_f32_16x16x32_bf16(A, Bhi[kc], a1, 0,0,0);
        a2 = __builtin_amdgcn_mfma_f32_16x16x32_bf16(A, Blo[kc], a2, 0,0,0);
      }
      if (l4 == 0){
        #pragma unroll
        for (int r = 0; r < 4; ++r) pre[wv][r][l15] = a1[r] + a2[r];
      }
      __threadfence_block();
      if (lane == 0)
        __hip_atomic_fetch_add(&pre_cnt, 1, __ATOMIC_RELAXED, WGSC);
    }
  } else {
    // ---------------- pointwise wave: 4 rows x 16 units ----------------
    const int bl = lane >> 4, uu = lane & 15;
    const int b = gid*RPG + bl, u = wgi*UPW + uu;
    float c_st = 0.f, h_st = 0.f;
    // prologue prefetch
    float cxi,cxf,cxo,cxg,cxj,cxk,cmm;
    {
      const int t0 = reverse ? (TT-1) : 0;
      const size_t xb = ((size_t)t0*BB + b)*XH + u;
      cxi = bf2f(xp[xb]);        cxf = bf2f(xp[xb +   HH]);
      cxo = bf2f(xp[xb + 2*HH]); cxg = bf2f(xp[xb + 3*HH]);
      cxj = bf2f(xp[xb + 4*HH]); cxk = bf2f(xp[xb + 5*HH]);
      cmm = masks[t0*BB + b];
    }
    for (int s = 0; s < TT; ++s){
      const int t = reverse ? (TT-1-s) : s;
      float p0=0,p1=0,p2=0,p3=0,p4=0;
      if (s > 0){
        const int tgt = 5*s;
        while (__hip_atomic_load(&pre_cnt, __ATOMIC_RELAXED, WGSC) < tgt){}
        p0 = pre[0][bl][uu]; p1 = pre[1][bl][uu]; p2 = pre[2][bl][uu];
        p3 = pre[3][bl][uu]; p4 = pre[4][bl][uu];
      }
      float ig = sigm(p0 + cxi);
      float fg = sigm(p1 + cxf + 1.0f);
      float og = sigm(p2 + cxo);
      float tg = sigm(p3 + cxg);
      float jg = tanh_f(p4 + cxj);
      float cn = fg*c_st + ig*jg;
      cn = cmm*cn + (1.f-cmm)*c_st;
      float hn = tg*og*tanh_f(cn) + (1.f-tg)*cxk;
      hn = cmm*hn + (1.f-cmm)*h_st;
      c_st = cn; h_st = hn;
      // pack 64 bf16 via LDS, publish as 16x 8B relaxed atomics
      pwl[bl*16 + uu] = f2bf(hn);
      __threadfence_block();
      if (lane < 16){
        int r = lane >> 2, q = lane & 3;
        u64 v = *(const u64*)&pwl[r*16 + q*4];
        u64* dstp = (u64*)(abf + ((size_t)t*BB + gid*RPG + r)*HH + wgi*UPW + q*4);
        __hip_atomic_store(dstp, v, __ATOMIC_RELAXED, SCOPE);
      }
      if (s < TT-1){
        asm volatile("s_waitcnt vmcnt(0)" ::: "memory");
        if (lane == 0)
          __hip_atomic_store(myslot, s+1, __ATOMIC_RELAXED, SCOPE);
        if (wgi == 0){
          const int tgt = s+1;
          for (;;){
            int v = (lane < NWG)
              ? __hip_atomic_load(slotbase + lane*16, __ATOMIC_RELAXED, SCOPE)
              : tgt;
            if (__all(v >= tgt)) break;
            __builtin_amdgcn_s_sleep(1);
          }
          if (lane == 0)
            __hip_atomic_store(ggo, tgt, __ATOMIC_RELAXED, SCOPE);
        }
      }
      if (outF) outF[((size_t)t*BB + b)*HH + u] = hn;
      if (s+1 < TT){
        const int t1 = reverse ? (t-1) : (t+1);
        const size_t xb = ((size_t)t1*BB + b)*XH + u;
        cxi = bf2f(xp[xb]);        cxf = bf2f(xp[xb +   HH]);
        cxo = bf2f(xp[xb + 2*HH]); cxg = bf2f(xp[xb + 3*HH]);
        cxj = bf2f(xp[xb + 4*HH]); cxk = bf2f(xp[xb + 5*HH]);
        cmm = masks[t1*BB + b];
      }
    }
    hT_out[(size_t)b*HH + u] = h_st;
    cT_out[(size_t)b*HH + u] = c_st;
  }
}

// ------------------------------- launch ---------------------------------------
extern "C" void kernel_launch(void* const* d_in, const int* in_sizes, int n_in,
                              void* d_out, int out_size, void* d_ws, size_t ws_size,
                              hipStream_t stream)
{
  const float* x = nullptr; const float* masks = nullptr;
  const float* wih[4] = {}; const float* bih[4] = {}; const float* whh[4] = {};
  int nw = 0, nb = 0, nh = 0;
  for (int i = 0; i < n_in; ++i){
    const int sz = in_sizes[i];
    const float* p = (const float*)d_in[i];
    if      (sz == TT*BB*HH){ if (!x) x = p; }
    else if (sz == TT*BB)   { if (!masks) masks = p; }
    else if (sz == XH*HH)   { if (nw < 4) wih[nw++] = p; }
    else if (sz == XH)      { if (nb < 4) bih[nb++] = p; }
    else if (sz == GH*HH)   { if (nh < 4) whh[nh++] = p; }
  }
  float* out = (float*)d_out;
  if (!x || !masks || nw != 4 || nb != 4 || nh != 4){
    fill_sentinel_f<<<512, 256, 0, stream>>>(out, out_size, 777.0f);
    return;
  }

  char* ws = (char*)d_ws;
  size_t off = 0;
  auto alloc = [&](size_t bytes)->void*{
    void* p = ws + off; off += (bytes + 255) & ~(size_t)255; return p;
  };
  unsigned short* xbf   = (unsigned short*)alloc((size_t)TT*BB*HH*2);  // 16.8 MB
  unsigned short* abf   = (unsigned short*)alloc((size_t)TT*BB*HH*2);  // 16.8 MB
  unsigned short* wbf   = (unsigned short*)alloc((size_t)XH*HH*2);     //  3.1 MB
  unsigned short* xproj = (unsigned short*)alloc((size_t)TT*BB*XH*2);  // 50.3 MB
  int*            slots = (int*)alloc((size_t)4*NGRP*NWG*16*4);        //  64 KB
  int*            go    = (int*)alloc((size_t)4*NGRP*16*4);            //   2 KB

  (void)hipMemsetAsync(slots, 0, (size_t)4*NGRP*NWG*16*4, stream);
  (void)hipMemsetAsync(go,    0, (size_t)4*NGRP*16*4, stream);

  const int thr = 256;
  auto cgrid = [&](int n){ int g = (n/4 + thr - 1)/thr; return g > 2048 ? 2048 : g; };
  conv_f2bf<<<cgrid(TT*BB*HH), thr, 0, stream>>>(x, xbf, TT*BB*HH);

  float* hn = out + (size_t)TT*BB*HH;
  float* cn = hn + (size_t)4*BB*HH;

  for (int L = 0; L < 4; ++L){
    const int rev = L & 1;
    conv_f2bf<<<cgrid(XH*HH), thr, 0, stream>>>(wih[L], wbf, XH*HH);
    gemm_bt<<<dim3(XH/BN, (TT*BB)/BM), 256, 0, stream>>>(
        (L == 0 ? xbf : abf), wbf, bih[L], xproj, TT*BB, XH, HH);

    lstm_scan_v7<<<NGRP*NWG, 384, 0, stream>>>(
        xproj, whh[L], masks, abf,
        (L == 3) ? out : nullptr,
        hn + (size_t)L*BB*HH, cn + (size_t)L*BB*HH,
        slots + (size_t)L*NGRP*NWG*16, go + (size_t)L*NGRP*16,
        rev);
  }
}

// Round 16
// 8979.251 us; speedup vs baseline: 1.7021x; 1.1347x over previous
//
#include <hip/hip_runtime.h>
#include <hip/hip_bf16.h>
#include <stdint.h>
#include <stddef.h>
#include <math.h>

#define HH 512
#define TT 512
#define BB 32
#define XH 3072   // 6*H
#define GH 2560   // 5*H
#define NWG 32    // unit-partition WGs per group
#define UPW 16    // units per WG
#define NGRP 2    // row-groups
#define RPG 16    // rows per group
#define KCH 16    // k chunks of 32
#define HSK 520   // hs kc-chunk stride in shorts (bank-spread)
#define SCOPE __HIP_MEMORY_SCOPE_AGENT
#define WGSC  __HIP_MEMORY_SCOPE_WORKGROUP

typedef __attribute__((ext_vector_type(8))) short bf16x8;
typedef __attribute__((ext_vector_type(4))) float f32x4;
typedef unsigned long long u64;

__device__ __forceinline__ float bf2f(unsigned short u){
  union{float f; unsigned int i;} v; v.i = ((unsigned int)u)<<16; return v.f;
}
__device__ __forceinline__ unsigned short f2bf(float f){
  union{float f; unsigned int i;} v; v.f=f;
  unsigned int x=v.i;
  return (unsigned short)((x + 0x7FFFu + ((x>>16)&1u))>>16);
}
__device__ __forceinline__ float sigm(float x){ return 1.f/(1.f+__expf(-x)); }
__device__ __forceinline__ float tanh_f(float x){ return 1.f - 2.f/(__expf(2.f*x)+1.f); }

__global__ void fill_sentinel_f(float* out, int n, float v){
  int i = blockIdx.x*blockDim.x + threadIdx.x;
  int stride = gridDim.x*blockDim.x;
  for (; i < n; i += stride) out[i] = v;
}

__global__ void conv_f2bf(const float* __restrict__ in, unsigned short* __restrict__ out, int n){
  int i = (blockIdx.x*blockDim.x + threadIdx.x)*4;
  int stride = gridDim.x*blockDim.x*4;
  for (; i < n; i += stride){
    float4 v = *(const float4*)(in + i);
    ushort4 o; o.x=f2bf(v.x); o.y=f2bf(v.y); o.z=f2bf(v.z); o.w=f2bf(v.w);
    *(ushort4*)(out + i) = o;
  }
}

// ------- MFMA bf16 GEMM: C_bf16[M,N] = A_bf16[M,K] @ Bt_bf16[N,K]^T + bias ---
#define BM 128
#define BN 128
#define BKK 32

__global__ __launch_bounds__(256)
void gemm_bt(const unsigned short* __restrict__ A, const unsigned short* __restrict__ Bt,
             const float* __restrict__ bias, unsigned short* __restrict__ C,
             int M, int N, int K)
{
  __shared__ unsigned short Alds[BM*BKK];
  __shared__ unsigned short Blds[BN*BKK];
  const int tid = threadIdx.x;
  const int lane = tid & 63;
  const int w = tid >> 6;
  const int gm = blockIdx.y, gn = blockIdx.x;
  const int wm = (w>>1)*64, wn = (w&1)*64;
  const int l15 = lane & 15, l4 = lane >> 4;
  f32x4 acc[4][4] = {};
  for (int k0 = 0; k0 < K; k0 += BKK){
    __syncthreads();
    #pragma unroll
    for (int it = 0; it < 2; ++it){
      int id2 = it*256 + tid;
      int row = id2 >> 2, kc = (id2 & 3)*8;
      *(bf16x8*)&Alds[row*BKK + kc] = *(const bf16x8*)(A + (size_t)(gm*BM+row)*K + k0 + kc);
      *(bf16x8*)&Blds[row*BKK + kc] = *(const bf16x8*)(Bt + (size_t)(gn*BN+row)*K + k0 + kc);
    }
    __syncthreads();
    bf16x8 af[4], bfv[4];
    #pragma unroll
    for (int i=0;i<4;i++) af[i]  = *(const bf16x8*)&Alds[(wm + i*16 + l15)*BKK + l4*8];
    #pragma unroll
    for (int j=0;j<4;j++) bfv[j] = *(const bf16x8*)&Blds[(wn + j*16 + l15)*BKK + l4*8];
    #pragma unroll
    for (int i=0;i<4;i++)
      #pragma unroll
      for (int j=0;j<4;j++)
        acc[i][j] = __builtin_amdgcn_mfma_f32_16x16x32_bf16(af[i], bfv[j], acc[i][j], 0,0,0);
  }
  #pragma unroll
  for (int i=0;i<4;i++){
    int row0 = gm*BM + wm + i*16 + l4*4;
    #pragma unroll
    for (int j=0;j<4;j++){
      int col = gn*BN + wn + j*16 + l15;
      float bz = bias[col];
      #pragma unroll
      for (int r=0;r<4;r++)
        C[(size_t)(row0+r)*N + col] = f2bf(acc[i][j][r] + bz);
    }
  }
}

// ---- scan v8: 2 groups x 32 WGs x 8 waves; M=16 full-row tiles; direct poll -
__global__ __launch_bounds__(512)
void lstm_scan_v8(const unsigned short* __restrict__ xp, // [T*B][6H] bf16
                  const float* __restrict__ whh,         // [5H][H] f32
                  const float* __restrict__ masks,       // [T*B] f32
                  unsigned short* __restrict__ abf,      // [T*B][H] bf16 (atomics)
                  float* __restrict__ outF,              // [T*B][H] f32 or null
                  float* __restrict__ hT_out, float* __restrict__ cT_out,
                  int* __restrict__ flags,               // [NGRP][NWG][16] zeroed
                  int reverse)
{
  __shared__ __align__(16) unsigned short hs[KCH*HSK];   // 16.6 KB
  __shared__ float pre[5][RPG][17];                      // 5.4 KB
  __shared__ unsigned short xps[2][6][RPG][16];          // 6 KB
  __shared__ float mlds[2][RPG];
  __shared__ __align__(8) unsigned short pwl[RPG*16];
  __shared__ int go_l;

  const int gid = blockIdx.x & 1;
  const int wgi = blockIdx.x >> 1;
  const int tid = threadIdx.x, wv = tid >> 6, lane = tid & 63;
  const int l15 = lane & 15, l4 = lane >> 4;
  const int u0 = wgi*UPW;
  const int r0 = gid*RPG;
  int* gflags = flags + gid*NWG*16;
  int* myflag = gflags + wgi*16;

  if (tid == 0) go_l = 0;

  // dot waves: B fragments (hi+lo split bf16), loaded once
  bf16x8 Bhi[KCH], Blo[KCH];
  if (wv < 5){
    const float* wrow = whh + ((size_t)(wv*HH + u0 + l15))*HH + l4*8;
    #pragma unroll
    for (int kc = 0; kc < KCH; ++kc){
      float4 v0 = *(const float4*)(wrow + kc*32);
      float4 v1 = *(const float4*)(wrow + kc*32 + 4);
      float vv[8] = {v0.x,v0.y,v0.z,v0.w,v1.x,v1.y,v1.z,v1.w};
      bf16x8 hh, ll;
      #pragma unroll
      for (int j = 0; j < 8; ++j){
        unsigned short hb = f2bf(vv[j]);
        hh[j] = (short)hb;
        ll[j] = (short)f2bf(vv[j] - bf2f(hb));
      }
      Bhi[kc] = hh; Blo[kc] = ll;
    }
  }

  // prologue: wave6 stages xps[0]/mask for t0
  if (wv == 6){
    const int t0 = reverse ? (TT-1) : 0;
    #pragma unroll
    for (int it = 0; it < 3; ++it){
      int p = it*64 + lane;            // 192 pieces
      int half = p & 1, pg = p >> 1;   // pg 0..95
      int g = pg % 6, row = pg / 6;
      *(uint4*)&xps[0][g][row][half*8] =
        *(const uint4*)(xp + ((size_t)t0*BB + r0 + row)*XH + g*HH + u0 + half*8);
    }
    if (lane < RPG) mlds[0][lane] = masks[t0*BB + r0 + lane];
  }

  // pointwise state (wave 5)
  const int r4 = lane >> 4, uu = lane & 15;
  float c_st[4] = {0,0,0,0}, h_st[4] = {0,0,0,0};

  for (int s = 0; s < TT; ++s){
    const int t = reverse ? (TT-1-s) : s;
    if (s > 0){
      if (wv == 7){
        for (;;){
          int v = (lane < NWG)
            ? __hip_atomic_load(gflags + lane*16, __ATOMIC_RELAXED, SCOPE) : s;
          if (__all(v >= s)) break;
          __builtin_amdgcn_s_sleep(1);
        }
        if (lane == 0) __hip_atomic_store(&go_l, s, __ATOMIC_RELAXED, WGSC);
      } else {
        while (__hip_atomic_load(&go_l, __ATOMIC_RELAXED, WGSC) < s)
          __builtin_amdgcn_s_sleep(1);
      }
      // stage h(t_prev): 2048 u64, all 8 waves, 4 each; bank-spread dest
      const int tp = reverse ? (t+1) : (t-1);
      const u64* src = (const u64*)(abf + ((size_t)tp*BB + r0)*HH);
      #pragma unroll
      for (int it = 0; it < 4; ++it){
        int j = it*512 + tid;
        u64 v = __hip_atomic_load(&src[j], __ATOMIC_RELAXED, SCOPE);
        int r = j >> 7, ww = j & 127;
        int kc = ww >> 3, q4 = (ww >> 1) & 3, half = ww & 1;
        *(u64*)&hs[kc*HSK + (q4*16 + r)*8 + half*4] = v;
      }
    }
    __syncthreads();   // hs + xps[s&1] ready
    if (s > 0 && wv < 5){
      f32x4 a1 = {0.f,0.f,0.f,0.f}, a2 = {0.f,0.f,0.f,0.f};
      #pragma unroll
      for (int kc = 0; kc < KCH; ++kc){
        bf16x8 A = *(const bf16x8*)&hs[kc*HSK + lane*8];
        a1 = __builtin_amdgcn_mfma_f32_16x16x32_bf16(A, Bhi[kc], a1, 0,0,0);
        a2 = __builtin_amdgcn_mfma_f32_16x16x32_bf16(A, Blo[kc], a2, 0,0,0);
      }
      #pragma unroll
      for (int r = 0; r < 4; ++r) pre[wv][l4*4 + r][l15] = a1[r] + a2[r];
    }
    if (wv == 6 && s+1 < TT){
      const int t1 = reverse ? (t-1) : (t+1);
      const int nb = (s+1) & 1;
      #pragma unroll
      for (int it = 0; it < 3; ++it){
        int p = it*64 + lane;
        int half = p & 1, pg = p >> 1;
        int g = pg % 6, row = pg / 6;
        *(uint4*)&xps[nb][g][row][half*8] =
          *(const uint4*)(xp + ((size_t)t1*BB + r0 + row)*XH + g*HH + u0 + half*8);
      }
      if (lane < RPG) mlds[nb][lane] = masks[t1*BB + r0 + lane];
    }
    __syncthreads();   // pre + xps[(s+1)&1] ready
    if (wv == 5){
      const int sb = s & 1;
      float hvals[4];
      #pragma unroll
      for (int i = 0; i < 4; ++i){
        const int row = r4 + i*4;
        float p0=0,p1=0,p2=0,p3=0,p4=0;
        if (s > 0){
          p0 = pre[0][row][uu]; p1 = pre[1][row][uu]; p2 = pre[2][row][uu];
          p3 = pre[3][row][uu]; p4 = pre[4][row][uu];
        }
        float xi = bf2f(xps[sb][0][row][uu]);
        float xf = bf2f(xps[sb][1][row][uu]);
        float xo = bf2f(xps[sb][2][row][uu]);
        float xg = bf2f(xps[sb][3][row][uu]);
        float xj = bf2f(xps[sb][4][row][uu]);
        float xk = bf2f(xps[sb][5][row][uu]);
        float mm = mlds[sb][row];
        float ig = sigm(p0 + xi);
        float fg = sigm(p1 + xf + 1.0f);
        float og = sigm(p2 + xo);
        float tg = sigm(p3 + xg);
        float jg = tanh_f(p4 + xj);
        float cn = fg*c_st[i] + ig*jg;
        cn = mm*cn + (1.f-mm)*c_st[i];
        float hn = tg*og*tanh_f(cn) + (1.f-tg)*xk;
        hn = mm*hn + (1.f-mm)*h_st[i];
        c_st[i] = cn; h_st[i] = hn;
        hvals[i] = hn;
        pwl[row*16 + uu] = f2bf(hn);
      }
      __threadfence_block();
      {
        int row = lane >> 2, q = lane & 3;
        u64 v = *(const u64*)&pwl[row*16 + q*4];
        u64* dstp = (u64*)(abf + ((size_t)t*BB + r0 + row)*HH + u0 + q*4);
        __hip_atomic_store(dstp, v, __ATOMIC_RELAXED, SCOPE);
      }
      asm volatile("s_waitcnt vmcnt(0)" ::: "memory");
      if (lane == 0)
        __hip_atomic_store(myflag, s+1, __ATOMIC_RELAXED, SCOPE);
      if (outF){
        #pragma unroll
        for (int i = 0; i < 4; ++i)
          outF[((size_t)t*BB + r0 + r4 + i*4)*HH + u0 + uu] = hvals[i];
      }
    }
  }
  if (wv == 5){
    #pragma unroll
    for (int i = 0; i < 4; ++i){
      int row = r0 + r4 + i*4;
      hT_out[(size_t)row*HH + u0 + uu] = h_st[i];
      cT_out[(size_t)row*HH + u0 + uu] = c_st[i];
    }
  }
}

// ------------------------------- launch ---------------------------------------
extern "C" void kernel_launch(void* const* d_in, const int* in_sizes, int n_in,
                              void* d_out, int out_size, void* d_ws, size_t ws_size,
                              hipStream_t stream)
{
  const float* x = nullptr; const float* masks = nullptr;
  const float* wih[4] = {}; const float* bih[4] = {}; const float* whh[4] = {};
  int nw = 0, nb = 0, nh = 0;
  for (int i = 0; i < n_in; ++i){
    const int sz = in_sizes[i];
    const float* p = (const float*)d_in[i];
    if      (sz == TT*BB*HH){ if (!x) x = p; }
    else if (sz == TT*BB)   { if (!masks) masks = p; }
    else if (sz == XH*HH)   { if (nw < 4) wih[nw++] = p; }
    else if (sz == XH)      { if (nb < 4) bih[nb++] = p; }
    else if (sz == GH*HH)   { if (nh < 4) whh[nh++] = p; }
  }
  float* out = (float*)d_out;
  if (!x || !masks || nw != 4 || nb != 4 || nh != 4){
    fill_sentinel_f<<<512, 256, 0, stream>>>(out, out_size, 777.0f);
    return;
  }

  char* ws = (char*)d_ws;
  size_t off = 0;
  auto alloc = [&](size_t bytes)->void*{
    void* p = ws + off; off += (bytes + 255) & ~(size_t)255; return p;
  };
  unsigned short* xbf   = (unsigned short*)alloc((size_t)TT*BB*HH*2);  // 16.8 MB
  unsigned short* abf   = (unsigned short*)alloc((size_t)TT*BB*HH*2);  // 16.8 MB
  unsigned short* wbf   = (unsigned short*)alloc((size_t)XH*HH*2);     //  3.1 MB
  unsigned short* xproj = (unsigned short*)alloc((size_t)TT*BB*XH*2);  // 50.3 MB
  int*            flags = (int*)alloc((size_t)4*NGRP*NWG*16*4);        //  16 KB

  (void)hipMemsetAsync(flags, 0, (size_t)4*NGRP*NWG*16*4, stream);

  const int thr = 256;
  auto cgrid = [&](int n){ int g = (n/4 + thr - 1)/thr; return g > 2048 ? 2048 : g; };
  conv_f2bf<<<cgrid(TT*BB*HH), thr, 0, stream>>>(x, xbf, TT*BB*HH);

  float* hn = out + (size_t)TT*BB*HH;
  float* cn = hn + (size_t)4*BB*HH;

  for (int L = 0; L < 4; ++L){
    const int rev = L & 1;
    conv_f2bf<<<cgrid(XH*HH), thr, 0, stream>>>(wih[L], wbf, XH*HH);
    gemm_bt<<<dim3(XH/BN, (TT*BB)/BM), 256, 0, stream>>>(
        (L == 0 ? xbf : abf), wbf, bih[L], xproj, TT*BB, XH, HH);

    lstm_scan_v8<<<NGRP*NWG, 512, 0, stream>>>(
        xproj, whh[L], masks, abf,
        (L == 3) ? out : nullptr,
        hn + (size_t)L*BB*HH, cn + (size_t)L*BB*HH,
        flags + (size_t)L*NGRP*NWG*16,
        rev);
  }
}

// Round 17
// 8586.667 us; speedup vs baseline: 1.7799x; 1.0457x over previous
//
#include <hip/hip_runtime.h>
#include <hip/hip_bf16.h>
#include <stdint.h>
#include <stddef.h>
#include <math.h>

#define HH 512
#define TT 512
#define BB 32
#define XH 3072   // 6*H
#define GH 2560   // 5*H
#define NWG 32    // unit-partition WGs per group
#define UPW 16    // units per WG
#define NGRP 2    // row-groups
#define RPG 16    // rows per group
#define KCH 16    // k chunks of 32
#define HSK 520   // hs kc-chunk stride in shorts (bank-spread)
#define POISON64 0xFFFFFFFFFFFFFFFFULL
#define SCOPE __HIP_MEMORY_SCOPE_AGENT

typedef __attribute__((ext_vector_type(8))) short bf16x8;
typedef __attribute__((ext_vector_type(4))) float f32x4;
typedef unsigned long long u64;

__device__ __forceinline__ float bf2f(unsigned short u){
  union{float f; unsigned int i;} v; v.i = ((unsigned int)u)<<16; return v.f;
}
__device__ __forceinline__ unsigned short f2bf(float f){
  union{float f; unsigned int i;} v; v.f=f;
  unsigned int x=v.i;
  return (unsigned short)((x + 0x7FFFu + ((x>>16)&1u))>>16);
}
__device__ __forceinline__ float sigm(float x){ return 1.f/(1.f+__expf(-x)); }
__device__ __forceinline__ float tanh_f(float x){ return 1.f - 2.f/(__expf(2.f*x)+1.f); }

__global__ void fill_sentinel_f(float* out, int n, float v){
  int i = blockIdx.x*blockDim.x + threadIdx.x;
  int stride = gridDim.x*blockDim.x;
  for (; i < n; i += stride) out[i] = v;
}

__global__ void conv_f2bf(const float* __restrict__ in, unsigned short* __restrict__ out, int n){
  int i = (blockIdx.x*blockDim.x + threadIdx.x)*4;
  int stride = gridDim.x*blockDim.x*4;
  for (; i < n; i += stride){
    float4 v = *(const float4*)(in + i);
    ushort4 o; o.x=f2bf(v.x); o.y=f2bf(v.y); o.z=f2bf(v.z); o.w=f2bf(v.w);
    *(ushort4*)(out + i) = o;
  }
}

// ------- MFMA bf16 GEMM: C_bf16[M,N] = A_bf16[M,K] @ Bt_bf16[N,K]^T + bias ---
#define BM 128
#define BN 128
#define BKK 32

__global__ __launch_bounds__(256)
void gemm_bt(const unsigned short* __restrict__ A, const unsigned short* __restrict__ Bt,
             const float* __restrict__ bias, unsigned short* __restrict__ C,
             int M, int N, int K)
{
  __shared__ unsigned short Alds[BM*BKK];
  __shared__ unsigned short Blds[BN*BKK];
  const int tid = threadIdx.x;
  const int lane = tid & 63;
  const int w = tid >> 6;
  const int gm = blockIdx.y, gn = blockIdx.x;
  const int wm = (w>>1)*64, wn = (w&1)*64;
  const int l15 = lane & 15, l4 = lane >> 4;
  f32x4 acc[4][4] = {};
  for (int k0 = 0; k0 < K; k0 += BKK){
    __syncthreads();
    #pragma unroll
    for (int it = 0; it < 2; ++it){
      int id2 = it*256 + tid;
      int row = id2 >> 2, kc = (id2 & 3)*8;
      *(bf16x8*)&Alds[row*BKK + kc] = *(const bf16x8*)(A + (size_t)(gm*BM+row)*K + k0 + kc);
      *(bf16x8*)&Blds[row*BKK + kc] = *(const bf16x8*)(Bt + (size_t)(gn*BN+row)*K + k0 + kc);
    }
    __syncthreads();
    bf16x8 af[4], bfv[4];
    #pragma unroll
    for (int i=0;i<4;i++) af[i]  = *(const bf16x8*)&Alds[(wm + i*16 + l15)*BKK + l4*8];
    #pragma unroll
    for (int j=0;j<4;j++) bfv[j] = *(const bf16x8*)&Blds[(wn + j*16 + l15)*BKK + l4*8];
    #pragma unroll
    for (int i=0;i<4;i++)
      #pragma unroll
      for (int j=0;j<4;j++)
        acc[i][j] = __builtin_amdgcn_mfma_f32_16x16x32_bf16(af[i], bfv[j], acc[i][j], 0,0,0);
  }
  #pragma unroll
  for (int i=0;i<4;i++){
    int row0 = gm*BM + wm + i*16 + l4*4;
    #pragma unroll
    for (int j=0;j<4;j++){
      int col = gn*BN + wn + j*16 + l15;
      float bz = bias[col];
      #pragma unroll
      for (int r=0;r<4;r++)
        C[(size_t)(row0+r)*N + col] = f2bf(acc[i][j][r] + bz);
    }
  }
}

// ---- scan v9: poison-poll value sync; 2 groups x 32 WGs x 8 waves -----------
__global__ __launch_bounds__(512)
void lstm_scan_v9(const unsigned short* __restrict__ xp, // [T*B][6H] bf16
                  const float* __restrict__ whh,         // [5H][H] f32
                  const float* __restrict__ masks,       // [T*B] f32
                  unsigned short* __restrict__ ab,       // [T*B][H] bf16, poisoned
                  float* __restrict__ outF,              // [T*B][H] f32 or null
                  float* __restrict__ hT_out, float* __restrict__ cT_out,
                  int reverse)
{
  __shared__ __align__(16) unsigned short hs[KCH*HSK];   // 16.6 KB
  __shared__ float pre[5][RPG][17];                      // 5.4 KB
  __shared__ unsigned short xps[2][6][RPG][16];          // 6 KB
  __shared__ float mlds[2][RPG];
  __shared__ __align__(8) unsigned short pwl[RPG*16];

  const int gid = blockIdx.x & 1;
  const int wgi = blockIdx.x >> 1;
  const int tid = threadIdx.x, wv = tid >> 6, lane = tid & 63;
  const int l15 = lane & 15, l4 = lane >> 4;
  const int u0 = wgi*UPW;
  const int r0 = gid*RPG;

  // dot waves: B fragments (hi+lo split bf16), loaded once
  bf16x8 Bhi[KCH], Blo[KCH];
  if (wv < 5){
    const float* wrow = whh + ((size_t)(wv*HH + u0 + l15))*HH + l4*8;
    #pragma unroll
    for (int kc = 0; kc < KCH; ++kc){
      float4 v0 = *(const float4*)(wrow + kc*32);
      float4 v1 = *(const float4*)(wrow + kc*32 + 4);
      float vv[8] = {v0.x,v0.y,v0.z,v0.w,v1.x,v1.y,v1.z,v1.w};
      bf16x8 hh, ll;
      #pragma unroll
      for (int j = 0; j < 8; ++j){
        unsigned short hb = f2bf(vv[j]);
        hh[j] = (short)hb;
        ll[j] = (short)f2bf(vv[j] - bf2f(hb));
      }
      Bhi[kc] = hh; Blo[kc] = ll;
    }
  }

  // prologue: wave6 stages xps[0]/mask for t0
  if (wv == 6){
    const int t0 = reverse ? (TT-1) : 0;
    #pragma unroll
    for (int it = 0; it < 3; ++it){
      int p = it*64 + lane;            // 192 pieces
      int half = p & 1, pg = p >> 1;   // pg 0..95
      int g = pg % 6, row = pg / 6;
      *(uint4*)&xps[0][g][row][half*8] =
        *(const uint4*)(xp + ((size_t)t0*BB + r0 + row)*XH + g*HH + u0 + half*8);
    }
    if (lane < RPG) mlds[0][lane] = masks[t0*BB + r0 + lane];
  }

  const int r4 = lane >> 4, uu = lane & 15;
  float c_st[4] = {0,0,0,0}, h_st[4] = {0,0,0,0};

  for (int s = 0; s < TT; ++s){
    const int t = reverse ? (TT-1-s) : s;
    if (s > 0){
      // stage h(t_prev): poll-load 2048 u64 (4/thread); non-poison => complete
      const int tp = reverse ? (t+1) : (t-1);
      const u64* src = (const u64*)(ab + ((size_t)tp*BB + r0)*HH);
      u64 v[4];
      #pragma unroll
      for (int it = 0; it < 4; ++it)
        v[it] = __hip_atomic_load(&src[it*512 + tid], __ATOMIC_RELAXED, SCOPE);
      for (;;){
        bool bad = false;
        #pragma unroll
        for (int it = 0; it < 4; ++it){
          if (v[it] == POISON64){
            v[it] = __hip_atomic_load(&src[it*512 + tid], __ATOMIC_RELAXED, SCOPE);
            bad = true;
          }
        }
        if (!bad) break;
        __builtin_amdgcn_s_sleep(1);
      }
      #pragma unroll
      for (int it = 0; it < 4; ++it){
        int j = it*512 + tid;
        int r = j >> 7, ww = j & 127;
        int kc = ww >> 3, q4 = (ww >> 1) & 3, half = ww & 1;
        *(u64*)&hs[kc*HSK + (q4*16 + r)*8 + half*4] = v[it];
      }
    }
    __syncthreads();   // hs + xps[s&1] ready
    if (s > 0 && wv < 5){
      f32x4 a1 = {0.f,0.f,0.f,0.f}, a2 = {0.f,0.f,0.f,0.f};
      #pragma unroll
      for (int kc = 0; kc < KCH; ++kc){
        bf16x8 A = *(const bf16x8*)&hs[kc*HSK + lane*8];
        a1 = __builtin_amdgcn_mfma_f32_16x16x32_bf16(A, Bhi[kc], a1, 0,0,0);
        a2 = __builtin_amdgcn_mfma_f32_16x16x32_bf16(A, Blo[kc], a2, 0,0,0);
      }
      #pragma unroll
      for (int r = 0; r < 4; ++r) pre[wv][l4*4 + r][l15] = a1[r] + a2[r];
    }
    if (wv == 6 && s+1 < TT){
      const int t1 = reverse ? (t-1) : (t+1);
      const int nb = (s+1) & 1;
      #pragma unroll
      for (int it = 0; it < 3; ++it){
        int p = it*64 + lane;
        int half = p & 1, pg = p >> 1;
        int g = pg % 6, row = pg / 6;
        *(uint4*)&xps[nb][g][row][half*8] =
          *(const uint4*)(xp + ((size_t)t1*BB + r0 + row)*XH + g*HH + u0 + half*8);
      }
      if (lane < RPG) mlds[nb][lane] = masks[t1*BB + r0 + lane];
    }
    __syncthreads();   // pre + xps[(s+1)&1] ready
    if (wv == 5){
      const int sb = s & 1;
      float hvals[4];
      #pragma unroll
      for (int i = 0; i < 4; ++i){
        const int row = r4 + i*4;
        float p0=0,p1=0,p2=0,p3=0,p4=0;
        if (s > 0){
          p0 = pre[0][row][uu]; p1 = pre[1][row][uu]; p2 = pre[2][row][uu];
          p3 = pre[3][row][uu]; p4 = pre[4][row][uu];
        }
        float xi = bf2f(xps[sb][0][row][uu]);
        float xf = bf2f(xps[sb][1][row][uu]);
        float xo = bf2f(xps[sb][2][row][uu]);
        float xg = bf2f(xps[sb][3][row][uu]);
        float xj = bf2f(xps[sb][4][row][uu]);
        float xk = bf2f(xps[sb][5][row][uu]);
        float mm = mlds[sb][row];
        float ig = sigm(p0 + xi);
        float fg = sigm(p1 + xf + 1.0f);
        float og = sigm(p2 + xo);
        float tg = sigm(p3 + xg);
        float jg = tanh_f(p4 + xj);
        float cn = fg*c_st[i] + ig*jg;
        cn = mm*cn + (1.f-mm)*c_st[i];
        float hn = tg*og*tanh_f(cn) + (1.f-tg)*xk;
        hn = mm*hn + (1.f-mm)*h_st[i];
        c_st[i] = cn; h_st[i] = hn;
        hvals[i] = hn;
        pwl[row*16 + uu] = f2bf(hn);
      }
      __threadfence_block();
      {
        int row = lane >> 2, q = lane & 3;
        u64 v = *(const u64*)&pwl[row*16 + q*4];
        u64* dstp = (u64*)(ab + ((size_t)t*BB + r0 + row)*HH + u0 + q*4);
        __hip_atomic_store(dstp, v, __ATOMIC_RELAXED, SCOPE);
      }
      if (outF){
        #pragma unroll
        for (int i = 0; i < 4; ++i)
          outF[((size_t)t*BB + r0 + r4 + i*4)*HH + u0 + uu] = hvals[i];
      }
    }
  }
  if (wv == 5){
    #pragma unroll
    for (int i = 0; i < 4; ++i){
      int row = r0 + r4 + i*4;
      hT_out[(size_t)row*HH + u0 + uu] = h_st[i];
      cT_out[(size_t)row*HH + u0 + uu] = c_st[i];
    }
  }
}

// ------------------------------- launch ---------------------------------------
extern "C" void kernel_launch(void* const* d_in, const int* in_sizes, int n_in,
                              void* d_out, int out_size, void* d_ws, size_t ws_size,
                              hipStream_t stream)
{
  const float* x = nullptr; const float* masks = nullptr;
  const float* wih[4] = {}; const float* bih[4] = {}; const float* whh[4] = {};
  int nw = 0, nb = 0, nh = 0;
  for (int i = 0; i < n_in; ++i){
    const int sz = in_sizes[i];
    const float* p = (const float*)d_in[i];
    if      (sz == TT*BB*HH){ if (!x) x = p; }
    else if (sz == TT*BB)   { if (!masks) masks = p; }
    else if (sz == XH*HH)   { if (nw < 4) wih[nw++] = p; }
    else if (sz == XH)      { if (nb < 4) bih[nb++] = p; }
    else if (sz == GH*HH)   { if (nh < 4) whh[nh++] = p; }
  }
  float* out = (float*)d_out;
  if (!x || !masks || nw != 4 || nb != 4 || nh != 4){
    fill_sentinel_f<<<512, 256, 0, stream>>>(out, out_size, 777.0f);
    return;
  }

  char* ws = (char*)d_ws;
  size_t off = 0;
  auto alloc = [&](size_t bytes)->void*{
    void* p = ws + off; off += (bytes + 255) & ~(size_t)255; return p;
  };
  unsigned short* xbf   = (unsigned short*)alloc((size_t)TT*BB*HH*2);  // 16.8 MB
  unsigned short* ab0   = (unsigned short*)alloc((size_t)TT*BB*HH*2);  // 16.8 MB
  unsigned short* ab1   = (unsigned short*)alloc((size_t)TT*BB*HH*2);  // 16.8 MB
  unsigned short* wbf   = (unsigned short*)alloc((size_t)XH*HH*2);     //  3.1 MB
  unsigned short* xproj = (unsigned short*)alloc((size_t)TT*BB*XH*2);  // 50.3 MB

  const int thr = 256;
  auto cgrid = [&](int n){ int g = (n/4 + thr - 1)/thr; return g > 2048 ? 2048 : g; };
  conv_f2bf<<<cgrid(TT*BB*HH), thr, 0, stream>>>(x, xbf, TT*BB*HH);

  float* hn = out + (size_t)TT*BB*HH;
  float* cn = hn + (size_t)4*BB*HH;

  unsigned short* ab[2] = {ab0, ab1};

  for (int L = 0; L < 4; ++L){
    const int rev = L & 1;
    unsigned short* cur  = ab[L & 1];
    const unsigned short* prev = (L == 0) ? xbf : ab[(L+1) & 1];
    conv_f2bf<<<cgrid(XH*HH), thr, 0, stream>>>(wih[L], wbf, XH*HH);
    gemm_bt<<<dim3(XH/BN, (TT*BB)/BM), 256, 0, stream>>>(
        prev, wbf, bih[L], xproj, TT*BB, XH, HH);
    // poison the h-exchange buffer: 0xFF bytes = bf16 NaN chunks (unreachable)
    (void)hipMemsetAsync(cur, 0xFF, (size_t)TT*BB*HH*2, stream);

    lstm_scan_v9<<<NGRP*NWG, 512, 0, stream>>>(
        xproj, whh[L], masks, cur,
        (L == 3) ? out : nullptr,
        hn + (size_t)L*BB*HH, cn + (size_t)L*BB*HH,
        rev);
  }
}

// Round 18
// 8047.453 us; speedup vs baseline: 1.8991x; 1.0670x over previous
//
#include <hip/hip_runtime.h>
#include <hip/hip_bf16.h>
#include <stdint.h>
#include <stddef.h>
#include <math.h>

#define HH 512
#define TT 512
#define BB 32
#define XH 3072   // 6*H
#define GH 2560   // 5*H
#define NWG 32    // unit-partition WGs per group
#define UPW 16    // units per WG
#define NGRP 2    // row-groups
#define RPG 16    // rows per group
#define KCH 16    // k chunks of 32
#define HSK 520   // hs kc-chunk stride in shorts (bank-spread)
#define SCOPE __HIP_MEMORY_SCOPE_AGENT
#define WGSC  __HIP_MEMORY_SCOPE_WORKGROUP

typedef __attribute__((ext_vector_type(8))) short bf16x8;
typedef __attribute__((ext_vector_type(4))) float f32x4;
typedef unsigned long long u64;

__device__ __forceinline__ float bf2f(unsigned short u){
  union{float f; unsigned int i;} v; v.i = ((unsigned int)u)<<16; return v.f;
}
__device__ __forceinline__ unsigned short f2bf(float f){
  union{float f; unsigned int i;} v; v.f=f;
  unsigned int x=v.i;
  return (unsigned short)((x + 0x7FFFu + ((x>>16)&1u))>>16);
}
__device__ __forceinline__ float sigm(float x){ return 1.f/(1.f+__expf(-x)); }
__device__ __forceinline__ float tanh_f(float x){ return 1.f - 2.f/(__expf(2.f*x)+1.f); }

__global__ void fill_sentinel_f(float* out, int n, float v){
  int i = blockIdx.x*blockDim.x + threadIdx.x;
  int stride = gridDim.x*blockDim.x;
  for (; i < n; i += stride) out[i] = v;
}

__global__ void conv_f2bf(const float* __restrict__ in, unsigned short* __restrict__ out, int n){
  int i = (blockIdx.x*blockDim.x + threadIdx.x)*4;
  int stride = gridDim.x*blockDim.x*4;
  for (; i < n; i += stride){
    float4 v = *(const float4*)(in + i);
    ushort4 o; o.x=f2bf(v.x); o.y=f2bf(v.y); o.z=f2bf(v.z); o.w=f2bf(v.w);
    *(ushort4*)(out + i) = o;
  }
}

// ------- MFMA bf16 GEMM: C_bf16[M,N] = A_bf16[M,K] @ Bt_bf16[N,K]^T + bias ---
#define BM 128
#define BN 128
#define BKK 32

__global__ __launch_bounds__(256)
void gemm_bt(const unsigned short* __restrict__ A, const unsigned short* __restrict__ Bt,
             const float* __restrict__ bias, unsigned short* __restrict__ C,
             int M, int N, int K)
{
  __shared__ unsigned short Alds[BM*BKK];
  __shared__ unsigned short Blds[BN*BKK];
  const int tid = threadIdx.x;
  const int lane = tid & 63;
  const int w = tid >> 6;
  const int gm = blockIdx.y, gn = blockIdx.x;
  const int wm = (w>>1)*64, wn = (w&1)*64;
  const int l15 = lane & 15, l4 = lane >> 4;
  f32x4 acc[4][4] = {};
  for (int k0 = 0; k0 < K; k0 += BKK){
    __syncthreads();
    #pragma unroll
    for (int it = 0; it < 2; ++it){
      int id2 = it*256 + tid;
      int row = id2 >> 2, kc = (id2 & 3)*8;
      *(bf16x8*)&Alds[row*BKK + kc] = *(const bf16x8*)(A + (size_t)(gm*BM+row)*K + k0 + kc);
      *(bf16x8*)&Blds[row*BKK + kc] = *(const bf16x8*)(Bt + (size_t)(gn*BN+row)*K + k0 + kc);
    }
    __syncthreads();
    bf16x8 af[4], bfv[4];
    #pragma unroll
    for (int i=0;i<4;i++) af[i]  = *(const bf16x8*)&Alds[(wm + i*16 + l15)*BKK + l4*8];
    #pragma unroll
    for (int j=0;j<4;j++) bfv[j] = *(const bf16x8*)&Blds[(wn + j*16 + l15)*BKK + l4*8];
    #pragma unroll
    for (int i=0;i<4;i++)
      #pragma unroll
      for (int j=0;j<4;j++)
        acc[i][j] = __builtin_amdgcn_mfma_f32_16x16x32_bf16(af[i], bfv[j], acc[i][j], 0,0,0);
  }
  #pragma unroll
  for (int i=0;i<4;i++){
    int row0 = gm*BM + wm + i*16 + l4*4;
    #pragma unroll
    for (int j=0;j<4;j++){
      int col = gn*BN + wn + j*16 + l15;
      float bz = bias[col];
      #pragma unroll
      for (int r=0;r<4;r++)
        C[(size_t)(row0+r)*N + col] = f2bf(acc[i][j][r] + bz);
    }
  }
}

// ---- scan v10: UC flag sync (no acquires) + CACHED h staging ----------------
__global__ __launch_bounds__(512)
void lstm_scan_v10(const unsigned short* __restrict__ xp, // [T*B][6H] bf16
                   const float* __restrict__ whh,         // [5H][H] f32
                   const float* __restrict__ masks,       // [T*B] f32
                   unsigned short* __restrict__ ab,       // [T*B][H] bf16
                   float* __restrict__ outF,              // [T*B][H] f32 or null
                   float* __restrict__ hT_out, float* __restrict__ cT_out,
                   int* __restrict__ flags,               // [NGRP][NWG][16] zeroed
                   int reverse)
{
  __shared__ __align__(16) unsigned short hs[KCH*HSK];   // 16.6 KB
  __shared__ float pre[5][RPG][17];                      // 5.4 KB
  __shared__ unsigned short xps[2][6][RPG][16];          // 6 KB
  __shared__ float mlds[2][RPG];
  __shared__ __align__(8) unsigned short pwl[RPG*16];
  __shared__ int go_l;

  const int gid = blockIdx.x & 1;
  const int wgi = blockIdx.x >> 1;
  const int tid = threadIdx.x, wv = tid >> 6, lane = tid & 63;
  const int l15 = lane & 15, l4 = lane >> 4;
  const int u0 = wgi*UPW;
  const int r0 = gid*RPG;
  int* gflags = flags + gid*NWG*16;
  int* myflag = gflags + wgi*16;

  if (tid == 0) go_l = 0;

  // dot waves: B fragments (hi+lo split bf16), loaded once
  bf16x8 Bhi[KCH], Blo[KCH];
  if (wv < 5){
    const float* wrow = whh + ((size_t)(wv*HH + u0 + l15))*HH + l4*8;
    #pragma unroll
    for (int kc = 0; kc < KCH; ++kc){
      float4 v0 = *(const float4*)(wrow + kc*32);
      float4 v1 = *(const float4*)(wrow + kc*32 + 4);
      float vv[8] = {v0.x,v0.y,v0.z,v0.w,v1.x,v1.y,v1.z,v1.w};
      bf16x8 hh, ll;
      #pragma unroll
      for (int j = 0; j < 8; ++j){
        unsigned short hb = f2bf(vv[j]);
        hh[j] = (short)hb;
        ll[j] = (short)f2bf(vv[j] - bf2f(hb));
      }
      Bhi[kc] = hh; Blo[kc] = ll;
    }
  }

  // prologue: wave6 stages xps[0]/mask for t0
  if (wv == 6){
    const int t0 = reverse ? (TT-1) : 0;
    #pragma unroll
    for (int it = 0; it < 3; ++it){
      int p = it*64 + lane;            // 192 pieces
      int half = p & 1, pg = p >> 1;   // pg 0..95
      int g = pg % 6, row = pg / 6;
      *(uint4*)&xps[0][g][row][half*8] =
        *(const uint4*)(xp + ((size_t)t0*BB + r0 + row)*XH + g*HH + u0 + half*8);
    }
    if (lane < RPG) mlds[0][lane] = masks[t0*BB + r0 + lane];
  }

  const int r4 = lane >> 4, uu = lane & 15;
  float c_st[4] = {0,0,0,0}, h_st[4] = {0,0,0,0};
  __syncthreads();   // go_l init + xps[0]

  for (int s = 0; s < TT; ++s){
    const int t = reverse ? (TT-1-s) : s;
    if (s > 0){
      // flag-gated: wave7 polls the 32 producer flags (UC, relaxed) directly
      if (wv == 7){
        for (;;){
          int v = (lane < NWG)
            ? __hip_atomic_load(gflags + lane*16, __ATOMIC_RELAXED, SCOPE) : s;
          if (__all(v >= s)) break;
          __builtin_amdgcn_s_sleep(1);
        }
        if (lane == 0) __hip_atomic_store(&go_l, s, __ATOMIC_RELAXED, WGSC);
      } else {
        while (__hip_atomic_load(&go_l, __ATOMIC_RELAXED, WGSC) < s){}
      }
      // stage h(t_prev): 16 KB via CACHED uint4 loads (L2-dedup across WGs)
      const int tp = reverse ? (t+1) : (t-1);
      const uint4* src = (const uint4*)(ab + ((size_t)tp*BB + r0)*HH);
      #pragma unroll
      for (int it = 0; it < 2; ++it){
        int j = it*512 + tid;            // 1024 uint4
        int r = j >> 6, ww = j & 63;
        int kc = ww >> 2, q8 = ww & 3;
        *(uint4*)&hs[kc*HSK + (q8*16 + r)*8] = src[j];
      }
    }
    __syncthreads();   // hs + xps[s&1] ready
    if (s > 0 && wv < 5){
      f32x4 a1 = {0.f,0.f,0.f,0.f}, a2 = {0.f,0.f,0.f,0.f};
      #pragma unroll
      for (int kc = 0; kc < KCH; ++kc){
        bf16x8 A = *(const bf16x8*)&hs[kc*HSK + lane*8];
        a1 = __builtin_amdgcn_mfma_f32_16x16x32_bf16(A, Bhi[kc], a1, 0,0,0);
        a2 = __builtin_amdgcn_mfma_f32_16x16x32_bf16(A, Blo[kc], a2, 0,0,0);
      }
      #pragma unroll
      for (int r = 0; r < 4; ++r) pre[wv][l4*4 + r][l15] = a1[r] + a2[r];
    }
    if (wv == 6 && s+1 < TT){
      const int t1 = reverse ? (t-1) : (t+1);
      const int nb = (s+1) & 1;
      #pragma unroll
      for (int it = 0; it < 3; ++it){
        int p = it*64 + lane;
        int half = p & 1, pg = p >> 1;
        int g = pg % 6, row = pg / 6;
        *(uint4*)&xps[nb][g][row][half*8] =
          *(const uint4*)(xp + ((size_t)t1*BB + r0 + row)*XH + g*HH + u0 + half*8);
      }
      if (lane < RPG) mlds[nb][lane] = masks[t1*BB + r0 + lane];
    }
    __syncthreads();   // pre + xps[(s+1)&1] ready
    if (wv == 5){
      const int sb = s & 1;
      float hvals[4];
      #pragma unroll
      for (int i = 0; i < 4; ++i){
        const int row = r4 + i*4;
        float p0=0,p1=0,p2=0,p3=0,p4=0;
        if (s > 0){
          p0 = pre[0][row][uu]; p1 = pre[1][row][uu]; p2 = pre[2][row][uu];
          p3 = pre[3][row][uu]; p4 = pre[4][row][uu];
        }
        float xi = bf2f(xps[sb][0][row][uu]);
        float xf = bf2f(xps[sb][1][row][uu]);
        float xo = bf2f(xps[sb][2][row][uu]);
        float xg = bf2f(xps[sb][3][row][uu]);
        float xj = bf2f(xps[sb][4][row][uu]);
        float xk = bf2f(xps[sb][5][row][uu]);
        float mm = mlds[sb][row];
        float ig = sigm(p0 + xi);
        float fg = sigm(p1 + xf + 1.0f);
        float og = sigm(p2 + xo);
        float tg = sigm(p3 + xg);
        float jg = tanh_f(p4 + xj);
        float cn = fg*c_st[i] + ig*jg;
        cn = mm*cn + (1.f-mm)*c_st[i];
        float hn = tg*og*tanh_f(cn) + (1.f-tg)*xk;
        hn = mm*hn + (1.f-mm)*h_st[i];
        c_st[i] = cn; h_st[i] = hn;
        hvals[i] = hn;
        pwl[row*16 + uu] = f2bf(hn);
      }
      __threadfence_block();
      {
        int row = lane >> 2, q = lane & 3;
        u64 v = *(const u64*)&pwl[row*16 + q*4];
        u64* dstp = (u64*)(ab + ((size_t)t*BB + r0 + row)*HH + u0 + q*4);
        __hip_atomic_store(dstp, v, __ATOMIC_RELAXED, SCOPE);  // UC store
      }
      asm volatile("s_waitcnt vmcnt(0)" ::: "memory");  // data at coherence pt
      if (lane == 0)
        __hip_atomic_store(myflag, s+1, __ATOMIC_RELAXED, SCOPE);
      if (outF){
        #pragma unroll
        for (int i = 0; i < 4; ++i)
          outF[((size_t)t*BB + r0 + r4 + i*4)*HH + u0 + uu] = hvals[i];
      }
    }
  }
  if (wv == 5){
    #pragma unroll
    for (int i = 0; i < 4; ++i){
      int row = r0 + r4 + i*4;
      hT_out[(size_t)row*HH + u0 + uu] = h_st[i];
      cT_out[(size_t)row*HH + u0 + uu] = c_st[i];
    }
  }
}

// ------------------------------- launch ---------------------------------------
extern "C" void kernel_launch(void* const* d_in, const int* in_sizes, int n_in,
                              void* d_out, int out_size, void* d_ws, size_t ws_size,
                              hipStream_t stream)
{
  const float* x = nullptr; const float* masks = nullptr;
  const float* wih[4] = {}; const float* bih[4] = {}; const float* whh[4] = {};
  int nw = 0, nb = 0, nh = 0;
  for (int i = 0; i < n_in; ++i){
    const int sz = in_sizes[i];
    const float* p = (const float*)d_in[i];
    if      (sz == TT*BB*HH){ if (!x) x = p; }
    else if (sz == TT*BB)   { if (!masks) masks = p; }
    else if (sz == XH*HH)   { if (nw < 4) wih[nw++] = p; }
    else if (sz == XH)      { if (nb < 4) bih[nb++] = p; }
    else if (sz == GH*HH)   { if (nh < 4) whh[nh++] = p; }
  }
  float* out = (float*)d_out;
  if (!x || !masks || nw != 4 || nb != 4 || nh != 4){
    fill_sentinel_f<<<512, 256, 0, stream>>>(out, out_size, 777.0f);
    return;
  }

  char* ws = (char*)d_ws;
  size_t off = 0;
  auto alloc = [&](size_t bytes)->void*{
    void* p = ws + off; off += (bytes + 255) & ~(size_t)255; return p;
  };
  unsigned short* xbf   = (unsigned short*)alloc((size_t)TT*BB*HH*2);  // 16.8 MB
  unsigned short* ab0   = (unsigned short*)alloc((size_t)TT*BB*HH*2);  // 16.8 MB
  unsigned short* ab1   = (unsigned short*)alloc((size_t)TT*BB*HH*2);  // 16.8 MB
  unsigned short* wbf   = (unsigned short*)alloc((size_t)XH*HH*2);     //  3.1 MB
  unsigned short* xproj = (unsigned short*)alloc((size_t)TT*BB*XH*2);  // 50.3 MB
  int*            flags = (int*)alloc((size_t)4*NGRP*NWG*16*4);        //  16 KB

  (void)hipMemsetAsync(flags, 0, (size_t)4*NGRP*NWG*16*4, stream);

  const int thr = 256;
  auto cgrid = [&](int n){ int g = (n/4 + thr - 1)/thr; return g > 2048 ? 2048 : g; };
  conv_f2bf<<<cgrid(TT*BB*HH), thr, 0, stream>>>(x, xbf, TT*BB*HH);

  float* hn = out + (size_t)TT*BB*HH;
  float* cn = hn + (size_t)4*BB*HH;

  unsigned short* ab[2] = {ab0, ab1};

  for (int L = 0; L < 4; ++L){
    const int rev = L & 1;
    unsigned short* cur  = ab[L & 1];
    const unsigned short* prev = (L == 0) ? xbf : ab[(L+1) & 1];
    conv_f2bf<<<cgrid(XH*HH), thr, 0, stream>>>(wih[L], wbf, XH*HH);
    gemm_bt<<<dim3(XH/BN, (TT*BB)/BM), 256, 0, stream>>>(
        prev, wbf, bih[L], xproj, TT*BB, XH, HH);

    lstm_scan_v10<<<NGRP*NWG, 512, 0, stream>>>(
        xproj, whh[L], masks, cur,
        (L == 3) ? out : nullptr,
        hn + (size_t)L*BB*HH, cn + (size_t)L*BB*HH,
        flags + (size_t)L*NGRP*NWG*16,
        rev);
  }
}